// Round 6
// baseline (2722.530 us; speedup 1.0000x reference)
//
#include <hip/hip_runtime.h>

// DINOMIMICClassification: per-sample 3-layer expert MLP (E=16,B=512,D=1536,H=768,T=2).
// R6: R0 tile structure + register-staged double buffering (T14), FLATTENED.
// R5 lesson: nested lambdas capturing staging float4s by reference defeated SROA ->
// staging state lived in scratch (WRITE 1.2GB, VALUBusy 2.4%). Here the whole pass is
// a flat __forceinline__ template function with named locals; no closures.
// Pass width adapts (SPT=2 for <=32 samples, SPT=4 otherwise). W read exactly once.

namespace {
constexpr int NE = 16, NB = 512, ND = 1536, NH = 768;
constexpr int CT = 64;            // cols per block tile
constexpr int KT = 32;            // k rows per LDS stage
constexpr int NCT = NH / CT;      // 12
constexpr int KS1 = 8, KS2 = 4;   // k-splits (KLEN = 192 both layers)
constexpr int KLEN = 192;
constexpr int NST = KLEN / KT;    // 6 stages

// One 64-sample pass: staged loads double-buffered through registers.
// Straight-line code, named locals only.
template<int SPT>
__device__ __forceinline__ void mm_pass(
    const float* __restrict__ act, int DIN,
    const float* __restrict__ Wp,          // &W[e][k0][c0]
    const int*   __restrict__ lst, int n, int s0, int k0,
    float (* __restrict__ Ws)[CT], float (* __restrict__ Xs)[64],
    int cg, int sg, int w_kk, int w_cc, int x_s, int x_kh,
    float* __restrict__ po)                // part + ks*NB*NH + c0 + cg*4
{
    float acc[SPT][4];
    #pragma unroll
    for (int i = 0; i < SPT; ++i)
        #pragma unroll
        for (int q = 0; q < 4; ++q) acc[i][q] = 0.f;

    const float* ga0 = act + (size_t)lst[s0 + x_s < n ? s0 + x_s : n - 1] * DIN + k0 + x_kh * 8;
    const bool   xok = (s0 + x_s < n);

    // ---- prologue: issue stage 0 ----
    const float* g = Wp + (size_t)w_kk * NH + w_cc;
    float4 rw0 = *(const float4*)g;
    float4 rw1 = *(const float4*)(g + (size_t)16 * NH);
    float4 rx0, rx1;
    if (xok) { rx0 = *(const float4*)ga0; rx1 = *(const float4*)(ga0 + 4); }
    else     { rx0 = make_float4(0.f,0.f,0.f,0.f); rx1 = rx0; }

    __syncthreads();   // previous pass readers done with LDS
    *(float4*)&Ws[w_kk][w_cc]      = rw0;
    *(float4*)&Ws[w_kk + 16][w_cc] = rw1;
    Xs[x_kh*8+0][x_s] = rx0.x; Xs[x_kh*8+1][x_s] = rx0.y;
    Xs[x_kh*8+2][x_s] = rx0.z; Xs[x_kh*8+3][x_s] = rx0.w;
    Xs[x_kh*8+4][x_s] = rx1.x; Xs[x_kh*8+5][x_s] = rx1.y;
    Xs[x_kh*8+6][x_s] = rx1.z; Xs[x_kh*8+7][x_s] = rx1.w;
    __syncthreads();

    #pragma unroll
    for (int t = 0; t < NST; ++t) {
        if (t + 1 < NST) {   // issue stage t+1 -> regs (in flight during FMA)
            const float* gn = Wp + (size_t)((t + 1) * KT + w_kk) * NH + w_cc;
            rw0 = *(const float4*)gn;
            rw1 = *(const float4*)(gn + (size_t)16 * NH);
            if (xok) {
                rx0 = *(const float4*)(ga0 + (t + 1) * KT);
                rx1 = *(const float4*)(ga0 + (t + 1) * KT + 4);
            }
        }
        #pragma unroll
        for (int k = 0; k < KT; ++k) {
            const float4 wv = *(const float4*)&Ws[k][cg * 4];
            if constexpr (SPT == 2) {
                const float2 xv = *(const float2*)&Xs[k][sg * 2];
                acc[0][0] += xv.x*wv.x; acc[0][1] += xv.x*wv.y;
                acc[0][2] += xv.x*wv.z; acc[0][3] += xv.x*wv.w;
                acc[1][0] += xv.y*wv.x; acc[1][1] += xv.y*wv.y;
                acc[1][2] += xv.y*wv.z; acc[1][3] += xv.y*wv.w;
            } else {
                const float4 xv = *(const float4*)&Xs[k][sg * 4];
                acc[0][0] += xv.x*wv.x; acc[0][1] += xv.x*wv.y; acc[0][2] += xv.x*wv.z; acc[0][3] += xv.x*wv.w;
                acc[1][0] += xv.y*wv.x; acc[1][1] += xv.y*wv.y; acc[1][2] += xv.y*wv.z; acc[1][3] += xv.y*wv.w;
                acc[2][0] += xv.z*wv.x; acc[2][1] += xv.z*wv.y; acc[2][2] += xv.z*wv.z; acc[2][3] += xv.z*wv.w;
                acc[3][0] += xv.w*wv.x; acc[3][1] += xv.w*wv.y; acc[3][2] += xv.w*wv.z; acc[3][3] += xv.w*wv.w;
            }
        }
        if (t + 1 < NST) {
            __syncthreads();   // all readers done with stage t
            *(float4*)&Ws[w_kk][w_cc]      = rw0;   // vmcnt waited here (late)
            *(float4*)&Ws[w_kk + 16][w_cc] = rw1;
            Xs[x_kh*8+0][x_s] = rx0.x; Xs[x_kh*8+1][x_s] = rx0.y;
            Xs[x_kh*8+2][x_s] = rx0.z; Xs[x_kh*8+3][x_s] = rx0.w;
            Xs[x_kh*8+4][x_s] = rx1.x; Xs[x_kh*8+5][x_s] = rx1.y;
            Xs[x_kh*8+6][x_s] = rx1.z; Xs[x_kh*8+7][x_s] = rx1.w;
            __syncthreads();
        }
    }

    #pragma unroll
    for (int si = 0; si < SPT; ++si) {
        const int s = s0 + sg * SPT + si;
        if (s < n)
            *(float4*)(po + (size_t)lst[s] * NH) =
                make_float4(acc[si][0], acc[si][1], acc[si][2], acc[si][3]);
    }
}

// part[ks][b][c] = sum_{k in split ks} act[b][k] * W[e_b][k][c]
template<int DIN, int KSN>
__global__ __launch_bounds__(256, 4)
void tile_mm(const float* __restrict__ act,   // [NB][DIN]
             const int*   __restrict__ head_idx,
             const float* __restrict__ W,     // [NE][DIN][NH]
             float*       __restrict__ part)  // [KSN][NB][NH]
{
    static_assert(DIN / KSN == KLEN, "KLEN mismatch");
    const int bid = blockIdx.x;
    const int e   = bid / (NCT * KSN);
    const int rem = bid % (NCT * KSN);
    const int j   = rem / KSN;
    const int ks  = rem % KSN;
    const int tid = threadIdx.x;

    __shared__ int lst[NB];
    __shared__ int n_sh;
    if (tid < 64) {   // wave 0: ballot-compact this expert's sample list
        int cnt = 0;
        for (int base = 0; base < NB; base += 64) {
            const int h = head_idx[base + tid];
            const unsigned long long m = __ballot(h == e);
            const int pos = cnt + __popcll(m & ((1ull << tid) - 1ull));
            if (h == e) lst[pos] = base + tid;
            cnt += __popcll(m);
        }
        if (tid == 0) n_sh = cnt;
    }
    __syncthreads();
    const int n = n_sh;
    if (n == 0) return;

    __shared__ float Ws[KT][CT];   // 8KB
    __shared__ float Xs[KT][64];   // 8KB

    const int cg = tid & 15;
    const int sg = tid >> 4;
    const int c0 = j * CT, k0 = ks * KLEN;
    const float* Wp = W + ((size_t)e * DIN + k0) * NH + c0;
    const int w_kk = tid >> 4;
    const int w_cc = (tid & 15) * 4;
    const int x_s  = tid & 63;
    const int x_kh = tid >> 6;
    float* po = part + (size_t)ks * NB * NH + c0 + cg * 4;

    for (int s0 = 0; s0 < n; s0 += 64) {
        if (n - s0 <= 32)
            mm_pass<2>(act, DIN, Wp, lst, n, s0, k0, Ws, Xs, cg, sg, w_kk, w_cc, x_s, x_kh, po);
        else
            mm_pass<4>(act, DIN, Wp, lst, n, s0, k0, Ws, Xs, cg, sg, w_kk, w_cc, x_s, x_kh, po);
    }
}

// h1[b][c] = relu(b1[e_b][c] + sum_ks part[ks][b][c])
template<int KSN>
__global__ __launch_bounds__(256)
void combine_relu(const float* __restrict__ part,   // [KSN][NB][NH]
                  const float* __restrict__ bias,   // [NE][NH]
                  const int*   __restrict__ head_idx,
                  float*       __restrict__ outp)   // [NB][NH]
{
    const int i = blockIdx.x * 256 + threadIdx.x;    // float4 index
    if (i >= NB * NH / 4) return;
    const int b  = i / (NH / 4);
    const int c4 = i % (NH / 4);
    constexpr int STR = NB * NH / 4;
    const float4* P = (const float4*)part;
    const int e = head_idx[b];
    const float4 bb = ((const float4*)bias)[e * (NH / 4) + c4];
    float sx = bb.x, sy = bb.y, sz = bb.z, sw = bb.w;
    #pragma unroll
    for (int ks = 0; ks < KSN; ++ks) {
        const float4 v = P[i + ks * STR];
        sx += v.x; sy += v.y; sz += v.z; sw += v.w;
    }
    float4 o;
    o.x = fmaxf(sx, 0.f); o.y = fmaxf(sy, 0.f);
    o.z = fmaxf(sz, 0.f); o.w = fmaxf(sw, 0.f);
    ((float4*)outp)[i] = o;
}

// out[b][t] = relu(sum_ks h2p[ks][b][:] + b2[e]) . W3[e][:,t] + b3[e][t]
template<int KSN>
__global__ __launch_bounds__(256)
void final_head(const float* __restrict__ h2p,  // [KSN][NB][NH]
                const float* __restrict__ b2,   // [NE][NH]
                const float* __restrict__ W3,   // [NE][NH][2]
                const float* __restrict__ b3,   // [NE][2]
                const int*   __restrict__ head_idx,
                float*       __restrict__ out)  // [NB][2]
{
    const int b    = blockIdx.x * 4 + (threadIdx.x >> 6);
    const int lane = threadIdx.x & 63;
    const int e    = head_idx[b];
    constexpr size_t STR = (size_t)NB * NH;
    float a0 = 0.f, a1 = 0.f;
    for (int h = lane; h < NH; h += 64) {
        const size_t o = (size_t)b * NH + h;
        float s = b2[e * NH + h];
        #pragma unroll
        for (int ks = 0; ks < KSN; ++ks) s += h2p[ks * STR + o];
        s = fmaxf(s, 0.f);
        const float2 w = *(const float2*)&W3[((size_t)e * NH + h) * 2];
        a0 += s * w.x;
        a1 += s * w.y;
    }
    #pragma unroll
    for (int off = 32; off > 0; off >>= 1) {
        a0 += __shfl_down(a0, off);
        a1 += __shfl_down(a1, off);
    }
    if (lane == 0) {
        out[b * 2 + 0] = a0 + b3[e * 2 + 0];
        out[b * 2 + 1] = a1 + b3[e * 2 + 1];
    }
}
} // namespace

extern "C" void kernel_launch(void* const* d_in, const int* in_sizes, int n_in,
                              void* d_out, int out_size, void* d_ws, size_t ws_size,
                              hipStream_t stream) {
    const float* x   = (const float*)d_in[0];
    const int*   hi  = (const int*)  d_in[1];
    const float* W1  = (const float*)d_in[2];
    const float* b1  = (const float*)d_in[3];
    const float* W2  = (const float*)d_in[4];
    const float* b2  = (const float*)d_in[5];
    const float* W3  = (const float*)d_in[6];
    const float* b3  = (const float*)d_in[7];
    float* out = (float*)d_out;

    // ws (fp32): h1p [KS1][B][H] 12.6MB (reused as h2p [KS2][B][H] 6.3MB) | h1 [B][H] 1.5MB
    float* h1p = (float*)d_ws;
    float* h1  = h1p + (size_t)KS1 * NB * NH;
    float* h2p = h1p;   // alias: h1p dead after combine_relu

    tile_mm<ND, KS1><<<NE * NCT * KS1, 256, 0, stream>>>(x,  hi, W1, h1p);
    combine_relu<KS1><<<(NB * NH / 4 + 255) / 256, 256, 0, stream>>>(h1p, b1, hi, h1);
    tile_mm<NH, KS2><<<NE * NCT * KS2, 256, 0, stream>>>(h1, hi, W2, h2p);
    final_head<KS2><<<NB / 4, 256, 0, stream>>>(h2p, b2, W3, b3, hi, out);
}